// Round 6
// baseline (4371.151 us; speedup 1.0000x reference)
//
#include <hip/hip_runtime.h>
#include <hip/hip_bf16.h>

// BiLSTM-CRF forward, MI355X gfx950.
// B=256, S=512, E=256, H=256, G=4H=1024, T=32, PAD=49999.
//
// Round-6 structure (= round 5 with fence-pair exchange, batched plain h loads):
//   K0 cvt_weights : fp32 -> bf16 for W_ih(2), W_hh(2), W_out
//   K1 embed_gather: x_bf[b][s][e] bf16
//   K2 lstm_rec    : 128 WGs x 256 thr. WG = (16-sentence group, dir, unit-chunk of 64).
//                    W_ih + W_hh rows fully VGPR-resident per wave. Per step:
//                    acc = bias + W_ih@x^T (prefetched x) + W_hh@h^T; h exchanged
//                    between quad WGs via plain global stores/loads bracketed by
//                    agent-scope release/acquire fences + relaxed exact-match flags.
//                    Emission (u=0, waves 0-1) after flag release (off critical path).
//   K3 crf_kernel  : real-path score + CRF forward (T=32); emit = emit_f + emit_b.

typedef __bf16 bf16x8 __attribute__((ext_vector_type(8)));
typedef float f32x4 __attribute__((ext_vector_type(4)));
typedef unsigned int uint4v __attribute__((ext_vector_type(4)));

__device__ __forceinline__ unsigned short f2bf(float f) {
  union { float f; unsigned int u; } v; v.f = f;
  unsigned int r = v.u + 0x7fffu + ((v.u >> 16) & 1u);   // RNE
  return (unsigned short)(r >> 16);
}
__device__ __forceinline__ float bf2f(unsigned int lo16) {
  union { unsigned int u; float f; } v; v.u = lo16 << 16;
  return v.f;
}
__device__ __forceinline__ float fsig(float x) {
  float e = __builtin_amdgcn_exp2f(-1.4426950408889634f * x);
  return __builtin_amdgcn_rcpf(1.0f + e);
}
__device__ __forceinline__ float ftanh(float x) {
  float e = __builtin_amdgcn_exp2f(2.8853900817779268f * x);
  return 1.0f - 2.0f * __builtin_amdgcn_rcpf(e + 1.0f);
}

// ---------------- K0: weight conversion fp32 -> bf16 ----------------
__global__ void cvt_weights(const float* __restrict__ wih_f, const float* __restrict__ wih_b,
                            const float* __restrict__ whh_f, const float* __restrict__ whh_b,
                            const float* __restrict__ wo,
                            unsigned short* __restrict__ wih, unsigned short* __restrict__ whh,
                            unsigned short* __restrict__ wout) {
  int t = blockIdx.x * 256 + threadIdx.x;
  int i = t * 4;
  const float* src; unsigned short* dst; int off;
  if (i < 524288)       { src = (i < 262144) ? wih_f : wih_b; off = i & 262143; dst = wih + i; }
  else if (i < 1048576) { int k = i - 524288;  src = (k < 262144) ? whh_f : whh_b; off = k & 262143; dst = whh + k; }
  else if (i < 1064960) { int k = i - 1048576; src = wo; off = k; dst = wout + k; }
  else return;
  f32x4 v = *(const f32x4*)(src + off);
  uint2 p;
  p.x = f2bf(v[0]) | ((unsigned int)f2bf(v[1]) << 16);
  p.y = f2bf(v[2]) | ((unsigned int)f2bf(v[3]) << 16);
  *(uint2*)dst = p;
}

// ---------------- K1: embedding gather -> bf16 ----------------
__global__ void embed_gather(const float* __restrict__ emb, const int* __restrict__ sent,
                             unsigned short* __restrict__ xo) {
  int tok  = blockIdx.x * 4 + (threadIdx.x >> 6);   // b*512+s
  int lane = threadIdx.x & 63;
  int tkn = sent[tok];
  f32x4 v = *(const f32x4*)(emb + (size_t)tkn * 256 + lane * 4);
  uint2 o;
  o.x = f2bf(v[0]) | ((unsigned int)f2bf(v[1]) << 16);
  o.y = f2bf(v[2]) | ((unsigned int)f2bf(v[3]) << 16);
  *(uint2*)(xo + (size_t)tok * 256 + lane * 4) = o;
}

// ---------------- K2: quad-split LSTM recurrence, W fully VGPR-resident ------
// grid 128: bx = u*32 + ch; ch = grp*2 + dir. 256 thr = 4 waves; wave w owns
// units [u*64 + w*16, +16): gate rows {g*256 + U0 + 0..15 : g=0..3}.
// hx: [32 ch][2 parity][1024 u64]; flg: [32 ch][2 parity][4 u][16] u32.
// Exchange: plain stores + fence(release,agent) + barrier + relaxed flag;
// consumer: relaxed polls + barrier + fence(acquire,agent) + plain dwordx4 loads.
__global__ __launch_bounds__(256, 1) void lstm_rec(
    const unsigned short* __restrict__ x_bf,   // [256][512][256]
    const unsigned short* __restrict__ wih,    // [2][1024][256]
    const unsigned short* __restrict__ whh,    // [2][1024][256]
    const unsigned short* __restrict__ wout,   // [32][512]
    const float* __restrict__ bih_f, const float* __restrict__ bhh_f,
    const float* __restrict__ bih_b, const float* __restrict__ bhh_b,
    const float* __restrict__ bout,
    const int* __restrict__ lens,
    unsigned short* __restrict__ emit_f,       // [256][512][32] bf16
    unsigned short* __restrict__ emit_b,       // [256][512][32] bf16
    unsigned long long* __restrict__ hx,
    unsigned int* __restrict__ flg)
{
  int bx = blockIdx.x;
  int u = bx >> 5, ch = bx & 31, dir = ch & 1, grp = ch >> 1, b0 = grp * 16;
  int tid = threadIdx.x, w = tid >> 6, lane = tid & 63, col = lane & 15, q = lane >> 4;
  int maxlen = lens[b0];              // sorted descending -> group max
  int mylen  = lens[b0 + col];
  int U0 = u * 64 + w * 16;
  const unsigned short* wihb = wih + (size_t)dir * 262144;
  const unsigned short* whhb = whh + (size_t)dir * 262144;

  // ---- weights fully into registers: 32 frags each ----
  bf16x8 wif[8][4], whf[8][4];
#pragma unroll
  for (int kt = 0; kt < 8; kt++)
#pragma unroll
    for (int t = 0; t < 4; t++) {
      size_t off = (size_t)(t * 256 + U0 + col) * 256 + kt * 32 + q * 8;
      wif[kt][t] = *(const bf16x8*)(wihb + off);
      whf[kt][t] = *(const bf16x8*)(whhb + off);
    }
  const float* bi = dir ? bih_b : bih_f;
  const float* bh = dir ? bhh_b : bhh_f;
  f32x4 bias4[4];
#pragma unroll
  for (int t = 0; t < 4; t++)
#pragma unroll
    for (int r = 0; r < 4; r++) {
      int row = t * 256 + U0 + q * 4 + r;
      bias4[t][r] = bi[row] + bh[row];
    }

  // ---- emission weights (u==0, waves 0-1): dir selects W_out half ----
  bool do_emit = (u == 0) && (w < 2);
  bf16x8 wof[8];
  f32x4 bo4 = (f32x4){0.f, 0.f, 0.f, 0.f};
  if (do_emit) {
#pragma unroll
    for (int kt = 0; kt < 8; kt++)
      wof[kt] = *(const bf16x8*)(wout + (size_t)(w * 16 + col) * 512 + dir * 256 + kt * 32 + q * 8);
    if (dir == 0) {
#pragma unroll
      for (int r = 0; r < 4; r++) bo4[r] = bout[w * 16 + q * 4 + r];
    }
  }
  unsigned short* ebase = dir ? emit_b : emit_f;

  unsigned long long* hxc = hx + (size_t)ch * 2048;   // 2 parities x 1024 u64
  unsigned int* flc = flg + ch * 128;                 // 2 parities x 4 u x 16

  // ---- x fragment prefetch for s=0 ----
  const unsigned short* xbase = x_bf + (size_t)(b0 + col) * 512 * 256;
  bf16x8 xb[8];
  {
    int se = dir ? (mylen - 1) : 0;
    const unsigned short* xp = xbase + (size_t)se * 256;
#pragma unroll
    for (int kt = 0; kt < 8; kt++) xb[kt] = *(const bf16x8*)(xp + kt * 32 + q * 8);
  }

  bf16x8 hbf[8];
  float c4[4] = {0.f, 0.f, 0.f, 0.f};
  int uk = u * 8 + w * 2 + (q >> 1);
  size_t hw_idx = (size_t)(uk * 16 + col) * 2 + (q & 1);

  for (int s = 0; s < maxlen; s++) {
    f32x4 acc[4];
#pragma unroll
    for (int t = 0; t < 4; t++) acc[t] = bias4[t];
    // ---- x-part (independent of peers) ----
#pragma unroll
    for (int kt = 0; kt < 8; kt++) {
      bf16x8 xv = xb[kt];
#pragma unroll
      for (int t = 0; t < 4; t++)
        acc[t] = __builtin_amdgcn_mfma_f32_16x16x32_bf16(wif[kt][t], xv, acc[t], 0, 0, 0);
    }
    // ---- prefetch x for s+1 (in flight across the peer wait) ----
    {
      int sn = (s + 1 < maxlen) ? s + 1 : s;
      int se = dir ? ((sn < mylen) ? (mylen - 1 - sn) : sn) : sn;
      const unsigned short* xp = xbase + (size_t)se * 256;
#pragma unroll
      for (int kt = 0; kt < 8; kt++) xb[kt] = *(const bf16x8*)(xp + kt * 32 + q * 8);
    }
    // ---- wait for h(s-1) from quad peers, then h-part ----
    if (s > 0) {
      int par = (s - 1) & 1;
      if (tid < 4 && tid != u) {
        unsigned want = (unsigned)s;
        int fi = (par * 4 + tid) * 16;
        int guard = 0;
        while (__hip_atomic_load(&flc[fi], __ATOMIC_RELAXED, __HIP_MEMORY_SCOPE_AGENT) != want) {
          if (++guard > 100000000) break;
        }
      }
      __syncthreads();
      __builtin_amdgcn_fence(__ATOMIC_ACQUIRE, "agent");
      // plain batched 16B loads of the full h vector (8 x dwordx4)
      const uint4v* hb128 = (const uint4v*)(hxc + (size_t)par * 1024);
#pragma unroll
      for (int kt = 0; kt < 8; kt++)
        hbf[kt] = __builtin_bit_cast(bf16x8, hb128[(kt * 4 + q) * 16 + col]);
#pragma unroll
      for (int kt = 0; kt < 8; kt++) {
        bf16x8 hv = hbf[kt];
#pragma unroll
        for (int t = 0; t < 4; t++)
          acc[t] = __builtin_amdgcn_mfma_f32_16x16x32_bf16(whf[kt][t], hv, acc[t], 0, 0, 0);
      }
    }
    // ---- gates -> h chunk -> exchange ----
    float hv[4];
#pragma unroll
    for (int r = 0; r < 4; r++) {
      float ig = acc[0][r], fg = acc[1][r], gg = acc[2][r], og = acc[3][r];
      float cn = fsig(fg) * c4[r] + fsig(ig) * ftanh(gg);
      c4[r] = cn;
      hv[r] = fsig(og) * ftanh(cn);
    }
    unsigned long long hp =
        (unsigned long long)(f2bf(hv[0]) | ((unsigned int)f2bf(hv[1]) << 16)) |
        ((unsigned long long)(f2bf(hv[2]) | ((unsigned int)f2bf(hv[3]) << 16)) << 32);
    hxc[(size_t)(s & 1) * 1024 + hw_idx] = hp;            // plain store
    __builtin_amdgcn_fence(__ATOMIC_RELEASE, "agent");    // drain this wave's stores
    __syncthreads();                                      // all waves drained
    if (tid == 0)
      __hip_atomic_store(&flc[((s & 1) * 4 + u) * 16], (unsigned)(s + 1),
                         __ATOMIC_RELAXED, __HIP_MEMORY_SCOPE_AGENT);

    // ---- fused emission for step s-1, AFTER flag: off the critical path ----
    if (s > 0 && do_emit) {
      f32x4 ea = bo4;
#pragma unroll
      for (int kt = 0; kt < 8; kt++)
        ea = __builtin_amdgcn_mfma_f32_16x16x32_bf16(wof[kt], hbf[kt], ea, 0, 0, 0);
      if (s - 1 < mylen) {
        int pos = dir ? (mylen - s) : (s - 1);
        unsigned short* dst = ebase + (((size_t)(b0 + col) * 512 + pos) * 32 + w * 16 + q * 4);
        uint2 pk;
        pk.x = f2bf(ea[0]) | ((unsigned int)f2bf(ea[1]) << 16);
        pk.y = f2bf(ea[2]) | ((unsigned int)f2bf(ea[3]) << 16);
        *(uint2*)dst = pk;
      }
    }
  }

  // ---- final emission for h(maxlen-1) ----
  if (u == 0) {
    int s = maxlen;
    int par = (s - 1) & 1;
    if (tid < 4 && tid != u) {
      unsigned want = (unsigned)s;
      int fi = (par * 4 + tid) * 16;
      int guard = 0;
      while (__hip_atomic_load(&flc[fi], __ATOMIC_RELAXED, __HIP_MEMORY_SCOPE_AGENT) != want) {
        if (++guard > 100000000) break;
      }
    }
    __syncthreads();
    __builtin_amdgcn_fence(__ATOMIC_ACQUIRE, "agent");
    if (do_emit) {
      const uint4v* hb128 = (const uint4v*)(hxc + (size_t)par * 1024);
      f32x4 ea = bo4;
#pragma unroll
      for (int kt = 0; kt < 8; kt++) {
        bf16x8 hv2 = __builtin_bit_cast(bf16x8, hb128[(kt * 4 + q) * 16 + col]);
        ea = __builtin_amdgcn_mfma_f32_16x16x32_bf16(wof[kt], hv2, ea, 0, 0, 0);
      }
      if (s - 1 < mylen) {
        int pos = dir ? (mylen - s) : (s - 1);
        unsigned short* dst = ebase + (((size_t)(b0 + col) * 512 + pos) * 32 + w * 16 + q * 4);
        uint2 pk;
        pk.x = f2bf(ea[0]) | ((unsigned int)f2bf(ea[1]) << 16);
        pk.y = f2bf(ea[2]) | ((unsigned int)f2bf(ea[3]) << 16);
        *(uint2*)dst = pk;
      }
    }
  }
}

// ---------------- K3: real-path score + CRF forward (bf16 emit in) ----------------
__global__ void crf_kernel(const unsigned short* __restrict__ emit_f,
                           const unsigned short* __restrict__ emit_b,
                           const float* __restrict__ trans, const int* __restrict__ tags,
                           const int* __restrict__ lens, float* __restrict__ out) {
  const float LOG2E = 1.4426950408889634f, LN2 = 0.6931471805599453f;
  int b = blockIdx.x, lane = threadIdx.x;
  int len = lens[b];
  const int* tg = tags + b * 512;

  float rs = 0.f;
  for (int s = lane; s < len; s += 64) {
    int t1 = tg[s];
    size_t idx = ((size_t)b * 512 + s) * 32 + t1;
    float e = bf2f(emit_f[idx]) + bf2f(emit_b[idx]);
    if (s > 0) e += trans[tg[s - 1] * 32 + t1];
    rs += e;
  }
#pragma unroll
  for (int m = 32; m; m >>= 1) rs += __shfl_xor(rs, m);

  int j = lane & 31, half = lane >> 5, i0 = half * 16;
  float tr[16];
#pragma unroll
  for (int ii = 0; ii < 16; ii++) tr[ii] = trans[(i0 + ii) * 32 + j];
  float alpha = bf2f(emit_f[(size_t)b * 512 * 32 + j]) + bf2f(emit_b[(size_t)b * 512 * 32 + j]);
  for (int s = 1; s < len; s++) {
    size_t idx = ((size_t)b * 512 + s) * 32 + j;
    float e = bf2f(emit_f[idx]) + bf2f(emit_b[idx]);
    float v[16]; float m1 = -1e30f;
#pragma unroll
    for (int ii = 0; ii < 16; ii++) { v[ii] = __shfl(alpha, i0 + ii) + tr[ii]; m1 = fmaxf(m1, v[ii]); }
    float m2 = fmaxf(m1, __shfl_xor(m1, 32));
    float sum = 0.f;
#pragma unroll
    for (int ii = 0; ii < 16; ii++) sum += __builtin_amdgcn_exp2f((v[ii] - m2) * LOG2E);
    sum += __shfl_xor(sum, 32);
    alpha = m2 + LN2 * __builtin_amdgcn_logf(sum) + e;   // amdgcn logf == log2
  }
  float mz = alpha;
#pragma unroll
  for (int m = 16; m; m >>= 1) mz = fmaxf(mz, __shfl_xor(mz, m));
  float sz = __builtin_amdgcn_exp2f((alpha - mz) * LOG2E);
#pragma unroll
  for (int m = 16; m; m >>= 1) sz += __shfl_xor(sz, m);
  float logz = mz + LN2 * __builtin_amdgcn_logf(sz);
  if (lane == 0) out[b] = logz - rs;
}

// ---------------- launch ----------------
extern "C" void kernel_launch(void* const* d_in, const int* in_sizes, int n_in,
                              void* d_out, int out_size, void* d_ws, size_t ws_size,
                              hipStream_t stream) {
  const float* emb   = (const float*)d_in[0];
  const float* Wih_f = (const float*)d_in[1];
  const float* Whh_f = (const float*)d_in[2];
  const float* bih_f = (const float*)d_in[3];
  const float* bhh_f = (const float*)d_in[4];
  const float* Wih_b = (const float*)d_in[5];
  const float* Whh_b = (const float*)d_in[6];
  const float* bih_b = (const float*)d_in[7];
  const float* bhh_b = (const float*)d_in[8];
  const float* Wout  = (const float*)d_in[9];
  const float* bout  = (const float*)d_in[10];
  const float* trans = (const float*)d_in[11];
  const int* sent = (const int*)d_in[12];
  const int* tags = (const int*)d_in[13];
  const int* lens = (const int*)d_in[14];
  float* out = (float*)d_out;

  // workspace layout (bytes), total 86,556,672
  char* ws = (char*)d_ws;
  if (ws_size < 86556672ull) return;
  unsigned short* x_bf    = (unsigned short*)(ws);                // 67,108,864
  unsigned short* emit_f  = (unsigned short*)(ws + 67108864);     //  8,388,608
  unsigned short* emit_b  = (unsigned short*)(ws + 75497472);     //  8,388,608
  unsigned short* wih_bf  = (unsigned short*)(ws + 83886080);     //  1,048,576
  unsigned short* whh_bf  = (unsigned short*)(ws + 84934656);     //  1,048,576
  unsigned short* wout_bf = (unsigned short*)(ws + 85983232);     //     32,768
  unsigned long long* hx  = (unsigned long long*)(ws + 86016000); //    524,288
  unsigned int*   flg     = (unsigned int*)(ws + 86540288);       //     16,384

  cvt_weights<<<1040, 256, 0, stream>>>(Wih_f, Wih_b, Whh_f, Whh_b, Wout,
                                        wih_bf, whh_bf, wout_bf);
  embed_gather<<<32768, 256, 0, stream>>>(emb, sent, x_bf);
  lstm_rec<<<128, 256, 0, stream>>>(x_bf, wih_bf, whh_bf, wout_bf,
                                    bih_f, bhh_f, bih_b, bhh_b, bout, lens,
                                    emit_f, emit_b, hx, flg);
  crf_kernel<<<256, 64, 0, stream>>>(emit_f, emit_b, trans, tags, lens, out);
}

// Round 7
// 2150.604 us; speedup vs baseline: 2.0325x; 2.0325x over previous
//
#include <hip/hip_runtime.h>
#include <hip/hip_bf16.h>

// BiLSTM-CRF forward, MI355X gfx950.
// B=256, S=512, E=256, H=256, G=4H=1024, T=32, PAD=49999.
//
// Round-7 structure (no cross-WG sync; fp8 W_hh fully VGPR-resident):
//   K0 cvt_weights : W_ih -> bf16, W_hh -> fp8 e4m3, W_out -> fp8 e4m3
//   per chunk (chunkS=64, 8 chunks):
//     K1 gx_gemm   : gx[dir][s_loc][b][g] = W_ih @ emb[sent[b][s_eff]] + bias (bf16).
//                    Block = 128 gates x 64 sentences x 8 s; W tile staged to LDS once,
//                    wave's 32 A-frags hoisted to VGPRs, then 8 s-iterations.
//     K2 lstm_rec  : 64 WGs x 512 thr; WG = (8-sentence group, dir) on ONE CU.
//                    W_hh fp8 frags fully VGPR-resident (128 regs/wave). Per step:
//                    acc = gx (prefetched bf16) + W_hh(fp8) @ h(fp8); gates f32;
//                    h exchanged via LDS fp8 parity buffers, 1 barrier/step;
//                    fused fp8 emission on waves 0-1; (h,c) state in global.
//   K3 crf_kernel  : real-path score + CRF forward (T=32); emit = emit_f + emit_b.

typedef __bf16 bf16x8 __attribute__((ext_vector_type(8)));
typedef float f32x4 __attribute__((ext_vector_type(4)));
typedef unsigned int uint4v __attribute__((ext_vector_type(4)));

__device__ __forceinline__ unsigned short f2bf(float f) {
  union { float f; unsigned int u; } v; v.f = f;
  unsigned int r = v.u + 0x7fffu + ((v.u >> 16) & 1u);   // RNE
  return (unsigned short)(r >> 16);
}
__device__ __forceinline__ float bf2f(unsigned int lo16) {
  union { unsigned int u; float f; } v; v.u = lo16 << 16;
  return v.f;
}
__device__ __forceinline__ float fsig(float x) {
  float e = __builtin_amdgcn_exp2f(-1.4426950408889634f * x);
  return __builtin_amdgcn_rcpf(1.0f + e);
}
__device__ __forceinline__ float ftanh(float x) {
  float e = __builtin_amdgcn_exp2f(2.8853900817779268f * x);
  return 1.0f - 2.0f * __builtin_amdgcn_rcpf(e + 1.0f);
}

// ---------------- K0: weight conversion ----------------
__global__ void cvt_weights(const float* __restrict__ wih_f, const float* __restrict__ wih_b,
                            const float* __restrict__ whh_f, const float* __restrict__ whh_b,
                            const float* __restrict__ wo,
                            unsigned short* __restrict__ wih,    // bf16 [2][1024][256]
                            unsigned char* __restrict__ whh8,    // fp8  [2][1024][256]
                            unsigned char* __restrict__ wout8) { // fp8  [32][512]
  int t = blockIdx.x * 256 + threadIdx.x;
  int i = t * 4;
  if (i < 524288) {
    const float* src = (i < 262144) ? wih_f : wih_b;
    f32x4 v = *(const f32x4*)(src + (i & 262143));
    uint2 p;
    p.x = f2bf(v[0]) | ((unsigned int)f2bf(v[1]) << 16);
    p.y = f2bf(v[2]) | ((unsigned int)f2bf(v[3]) << 16);
    *(uint2*)(wih + i) = p;
  } else if (i < 1048576) {
    int k = i - 524288;
    const float* src = (k < 262144) ? whh_f : whh_b;
    f32x4 v = *(const f32x4*)(src + (k & 262143));
    int r = 0;
    r = __builtin_amdgcn_cvt_pk_fp8_f32(v[0], v[1], r, false);
    r = __builtin_amdgcn_cvt_pk_fp8_f32(v[2], v[3], r, true);
    *(unsigned int*)(whh8 + k) = (unsigned int)r;
  } else if (i < 1064960) {
    int k = i - 1048576;
    f32x4 v = *(const f32x4*)(wo + k);
    int r = 0;
    r = __builtin_amdgcn_cvt_pk_fp8_f32(v[0], v[1], r, false);
    r = __builtin_amdgcn_cvt_pk_fp8_f32(v[2], v[3], r, true);
    *(unsigned int*)(wout8 + k) = (unsigned int)r;
  }
}

// ---------------- K1: gx = W_ih @ x(s_eff)^T + bias (bf16 out) ----------------
// grid (256, 2): x = nc(8) x bt(4) x ss(8); y = dir. 512 thr = 8 waves.
// Wave (ns = w>>2, cg = w&3): 64 gates x 16 sentences; W frags hoisted to VGPR.
__global__ __launch_bounds__(512, 2) void gx_gemm(
    const float* __restrict__ emb, const int* __restrict__ sent, const int* __restrict__ lens,
    const unsigned short* __restrict__ wih,
    const float* __restrict__ bih_f, const float* __restrict__ bhh_f,
    const float* __restrict__ bih_b, const float* __restrict__ bhh_b,
    unsigned short* __restrict__ gx,            // [2][64][256][1024] bf16
    int s0)
{
  __shared__ __align__(16) unsigned short wtile[128 * 264];
  __shared__ __align__(16) float btile[128];
  int dir = blockIdx.y;
  int bx  = blockIdx.x;
  int nc = bx >> 5, bt = (bx >> 3) & 3, ss = bx & 7;
  int n0 = nc * 128, bbase = bt * 64;
  int sbase = s0 + ss * 8;
  if (sbase >= lens[bbase]) return;   // sorted desc: lens[bbase] = tile max
  int tid = threadIdx.x, w = tid >> 6, lane = tid & 63, col = lane & 15, q = lane >> 4;
  int ns = w >> 2, cg = w & 3;

  const unsigned short* wsrc = wih + (size_t)dir * 262144;
#pragma unroll
  for (int it = 0; it < 8; it++) {
    int seg = it * 512 + tid;
    int row = seg >> 5, kc = (seg & 31) * 8;
    *(uint4v*)(wtile + row * 264 + kc) = *(const uint4v*)(wsrc + (size_t)(n0 + row) * 256 + kc);
  }
  const float* bi = dir ? bih_b : bih_f;
  const float* bh = dir ? bhh_b : bhh_f;
  if (tid < 128) btile[tid] = bi[n0 + tid] + bh[n0 + tid];
  __syncthreads();

  bf16x8 wf[8][4];
#pragma unroll
  for (int kt = 0; kt < 8; kt++)
#pragma unroll
    for (int nt = 0; nt < 4; nt++)
      wf[kt][nt] = *(const bf16x8*)(wtile + (ns * 64 + nt * 16 + col) * 264 + kt * 32 + q * 8);
  f32x4 bias[4];
#pragma unroll
  for (int nt = 0; nt < 4; nt++)
#pragma unroll
    for (int r = 0; r < 4; r++)
      bias[nt][r] = btile[ns * 64 + nt * 16 + q * 4 + r];

  int bidx = bbase + cg * 16 + col;
  int len = lens[bidx];
  const int* srow = sent + bidx * 512;

  for (int i = 0; i < 8; i++) {
    int s = sbase + i;
    int s_eff = dir ? ((s < len) ? (len - 1 - s) : s) : s;
    int token = srow[s_eff];
    const float* ep = emb + (size_t)token * 256;
    bf16x8 xf[8];
#pragma unroll
    for (int kt = 0; kt < 8; kt++) {
      f32x4 a0 = *(const f32x4*)(ep + kt * 32 + q * 8);
      f32x4 a1 = *(const f32x4*)(ep + kt * 32 + q * 8 + 4);
      uint4v pk;
      pk[0] = f2bf(a0[0]) | ((unsigned int)f2bf(a0[1]) << 16);
      pk[1] = f2bf(a0[2]) | ((unsigned int)f2bf(a0[3]) << 16);
      pk[2] = f2bf(a1[0]) | ((unsigned int)f2bf(a1[1]) << 16);
      pk[3] = f2bf(a1[2]) | ((unsigned int)f2bf(a1[3]) << 16);
      xf[kt] = __builtin_bit_cast(bf16x8, pk);
    }
    f32x4 acc[4];
#pragma unroll
    for (int nt = 0; nt < 4; nt++) acc[nt] = bias[nt];
#pragma unroll
    for (int kt = 0; kt < 8; kt++)
#pragma unroll
      for (int nt = 0; nt < 4; nt++)
        acc[nt] = __builtin_amdgcn_mfma_f32_16x16x32_bf16(wf[kt][nt], xf[kt], acc[nt], 0, 0, 0);
    size_t off = (((size_t)dir * 64 + (s - s0)) * 256 + bidx) * 1024 + n0 + ns * 64;
#pragma unroll
    for (int nt = 0; nt < 4; nt++) {
      uint2 pk;
      pk.x = f2bf(acc[nt][0]) | ((unsigned int)f2bf(acc[nt][1]) << 16);
      pk.y = f2bf(acc[nt][2]) | ((unsigned int)f2bf(acc[nt][3]) << 16);
      *(uint2*)(gx + off + nt * 16 + q * 4) = pk;
    }
  }
}

// ---------------- K2: LSTM recurrence chunk, fp8 W_hh VGPR-resident ----------------
// grid 64: bx = grp*2 + dir; WG = 8 sentences (cols 0..7 real), 512 thr = 8 waves.
// Wave w owns units [w*32, w*32+32): gate rows {g*256 + w*32 + a*16 + 0..15}.
__global__ __launch_bounds__(512, 2) void lstm_rec(
    const unsigned short* __restrict__ gx,     // [2][64][256][1024] bf16
    const unsigned char* __restrict__ whh8,    // [2][1024][256] fp8
    const unsigned char* __restrict__ wout8,   // [32][512] fp8
    const float* __restrict__ bout,
    const int* __restrict__ lens,
    unsigned short* __restrict__ emit_f, unsigned short* __restrict__ emit_b,
    unsigned short* __restrict__ h_state,      // [64][16][256] bf16
    float* __restrict__ c_state,               // [64][16][256] f32
    int s0, int first)
{
  __shared__ __align__(16) unsigned char hbuf[2][16 * 264];   // fp8 h, parity-buffered
  int bx = blockIdx.x;
  int dir = bx & 1, grp = bx >> 1, b0 = grp * 8;
  int tid = threadIdx.x, w = tid >> 6, lane = tid & 63, col = lane & 15, q = lane >> 4;
  int maxlen = lens[b0];
  if (s0 >= maxlen) return;
  int send = s0 + 64; if (send > maxlen) send = maxlen;
  int bcl = b0 + col; if (bcl > 255) bcl = 255;
  int mylen = lens[bcl];

  // ---- W_hh fp8 fragments fully into registers (64 x 8B = 128 VGPRs) ----
  const unsigned char* whb = whh8 + (size_t)dir * 262144;
  long wh[8][8];
#pragma unroll
  for (int kt = 0; kt < 8; kt++)
#pragma unroll
    for (int t = 0; t < 8; t++) {
      int row0 = (t & 3) * 256 + w * 32 + (t >> 2) * 16;
      wh[kt][t] = *(const long*)(whb + (size_t)(row0 + col) * 256 + kt * 32 + q * 8);
    }

  // ---- emission weights fp8 (waves 0-1) ----
  long wo8[8];
  f32x4 bo4 = (f32x4){0.f, 0.f, 0.f, 0.f};
  if (w < 2) {
#pragma unroll
    for (int kt = 0; kt < 8; kt++)
      wo8[kt] = *(const long*)(wout8 + (size_t)(w * 16 + col) * 512 + dir * 256 + kt * 32 + q * 8);
    if (dir == 0) {
#pragma unroll
      for (int r = 0; r < 4; r++) bo4[r] = bout[w * 16 + q * 4 + r];
    }
  }
  unsigned short* ebase = dir ? emit_b : emit_f;

  // ---- state restore ----
  size_t stoff = ((size_t)bx * 16 + col) * 256 + w * 32;
  float c8[8];
  long hf8[8];
  if (first) {
#pragma unroll
    for (int i = 0; i < 8; i++) c8[i] = 0.f;
#pragma unroll
    for (int i = 0; i < 8; i++) hf8[i] = 0;
  } else {
    int pf = (s0 + 1) & 1;
#pragma unroll
    for (int a = 0; a < 2; a++) {
      f32x4 cv = *(const f32x4*)(c_state + stoff + a * 16 + q * 4);
#pragma unroll
      for (int r = 0; r < 4; r++) c8[a * 4 + r] = cv[r];
      uint2 hb = *(const uint2*)(h_state + stoff + a * 16 + q * 4);
      float h0 = bf2f(hb.x & 0xffffu), h1 = bf2f(hb.x >> 16);
      float h2 = bf2f(hb.y & 0xffffu), h3 = bf2f(hb.y >> 16);
      int r8 = 0;
      r8 = __builtin_amdgcn_cvt_pk_fp8_f32(h0, h1, r8, false);
      r8 = __builtin_amdgcn_cvt_pk_fp8_f32(h2, h3, r8, true);
      *(unsigned int*)(&hbuf[pf][col * 264 + w * 32 + a * 16 + q * 4]) = (unsigned int)r8;
    }
    __syncthreads();
#pragma unroll
    for (int kt = 0; kt < 8; kt++)
      hf8[kt] = *(const long*)(&hbuf[pf][col * 264 + kt * 32 + q * 8]);
  }

  // ---- gx lane base + prefetch for s0 ----
  const unsigned short* gl = gx + ((size_t)dir * 64 * 256 + bcl) * 1024 + q * 4;
  uint2 gxr[8];
#pragma unroll
  for (int t = 0; t < 8; t++) {
    int row0 = (t & 3) * 256 + w * 32 + (t >> 2) * 16;
    gxr[t] = *(const uint2*)(gl + row0);
  }

  for (int s = s0; s < send; s++) {
    f32x4 acc[8];
#pragma unroll
    for (int t = 0; t < 8; t++) {
      f32x4 a;
      a[0] = bf2f(gxr[t].x & 0xffffu); a[1] = bf2f(gxr[t].x >> 16);
      a[2] = bf2f(gxr[t].y & 0xffffu); a[3] = bf2f(gxr[t].y >> 16);
      acc[t] = a;
    }
    // prefetch gx for s+1 (clamped)
    {
      int snl = (s + 1 < send) ? (s + 1 - s0) : (send - 1 - s0);
      const unsigned short* gn = gl + (size_t)snl * 262144;
#pragma unroll
      for (int t = 0; t < 8; t++) {
        int row0 = (t & 3) * 256 + w * 32 + (t >> 2) * 16;
        gxr[t] = *(const uint2*)(gn + row0);
      }
    }
    // h-part: fp8 MFMA, W resident
#pragma unroll
    for (int kt = 0; kt < 8; kt++) {
      long hv8 = hf8[kt];
#pragma unroll
      for (int t = 0; t < 8; t++)
        acc[t] = __builtin_amdgcn_mfma_f32_16x16x32_fp8_fp8(wh[kt][t], hv8, acc[t], 0, 0, 0);
    }
    // gates
    float hv[8];
#pragma unroll
    for (int a = 0; a < 2; a++)
#pragma unroll
      for (int r = 0; r < 4; r++) {
        float ig = acc[a * 4 + 0][r], fg = acc[a * 4 + 1][r];
        float gg = acc[a * 4 + 2][r], og = acc[a * 4 + 3][r];
        float cn = fsig(fg) * c8[a * 4 + r] + fsig(ig) * ftanh(gg);
        c8[a * 4 + r] = cn;
        hv[a * 4 + r] = fsig(og) * ftanh(cn);
      }
    // write fp8 h to LDS parity buffer
    int par = s & 1;
#pragma unroll
    for (int a = 0; a < 2; a++) {
      int r8 = 0;
      r8 = __builtin_amdgcn_cvt_pk_fp8_f32(hv[a * 4 + 0], hv[a * 4 + 1], r8, false);
      r8 = __builtin_amdgcn_cvt_pk_fp8_f32(hv[a * 4 + 2], hv[a * 4 + 3], r8, true);
      *(unsigned int*)(&hbuf[par][col * 264 + w * 32 + a * 16 + q * 4]) = (unsigned int)r8;
    }
    if (s == send - 1) {   // bf16 state save for next chunk
#pragma unroll
      for (int a = 0; a < 2; a++) {
        uint2 p;
        p.x = f2bf(hv[a * 4 + 0]) | ((unsigned int)f2bf(hv[a * 4 + 1]) << 16);
        p.y = f2bf(hv[a * 4 + 2]) | ((unsigned int)f2bf(hv[a * 4 + 3]) << 16);
        *(uint2*)(h_state + stoff + a * 16 + q * 4) = p;
      }
    }
    __syncthreads();
#pragma unroll
    for (int kt = 0; kt < 8; kt++)
      hf8[kt] = *(const long*)(&hbuf[par][col * 264 + kt * 32 + q * 8]);

    if (w < 2) {   // fused fp8 emission of h(s)
      f32x4 ea = bo4;
#pragma unroll
      for (int kt = 0; kt < 8; kt++)
        ea = __builtin_amdgcn_mfma_f32_16x16x32_fp8_fp8(wo8[kt], hf8[kt], ea, 0, 0, 0);
      if (col < 8 && s < mylen) {
        int pos = dir ? (mylen - 1 - s) : s;
        uint2 pk;
        pk.x = f2bf(ea[0]) | ((unsigned int)f2bf(ea[1]) << 16);
        pk.y = f2bf(ea[2]) | ((unsigned int)f2bf(ea[3]) << 16);
        *(uint2*)(ebase + (((size_t)(b0 + col) * 512 + pos) * 32 + w * 16 + q * 4)) = pk;
      }
    }
  }
  // c save
#pragma unroll
  for (int a = 0; a < 2; a++) {
    f32x4 cv;
#pragma unroll
    for (int r = 0; r < 4; r++) cv[r] = c8[a * 4 + r];
    *(f32x4*)(c_state + stoff + a * 16 + q * 4) = cv;
  }
}

// ---------------- K3: real-path score + CRF forward (bf16 emit in) ----------------
__global__ void crf_kernel(const unsigned short* __restrict__ emit_f,
                           const unsigned short* __restrict__ emit_b,
                           const float* __restrict__ trans, const int* __restrict__ tags,
                           const int* __restrict__ lens, float* __restrict__ out) {
  const float LOG2E = 1.4426950408889634f, LN2 = 0.6931471805599453f;
  int b = blockIdx.x, lane = threadIdx.x;
  int len = lens[b];
  const int* tg = tags + b * 512;

  float rs = 0.f;
  for (int s = lane; s < len; s += 64) {
    int t1 = tg[s];
    size_t idx = ((size_t)b * 512 + s) * 32 + t1;
    float e = bf2f(emit_f[idx]) + bf2f(emit_b[idx]);
    if (s > 0) e += trans[tg[s - 1] * 32 + t1];
    rs += e;
  }
#pragma unroll
  for (int m = 32; m; m >>= 1) rs += __shfl_xor(rs, m);

  int j = lane & 31, half = lane >> 5, i0 = half * 16;
  float tr[16];
#pragma unroll
  for (int ii = 0; ii < 16; ii++) tr[ii] = trans[(i0 + ii) * 32 + j];
  float alpha = bf2f(emit_f[(size_t)b * 512 * 32 + j]) + bf2f(emit_b[(size_t)b * 512 * 32 + j]);
  for (int s = 1; s < len; s++) {
    size_t idx = ((size_t)b * 512 + s) * 32 + j;
    float e = bf2f(emit_f[idx]) + bf2f(emit_b[idx]);
    float v[16]; float m1 = -1e30f;
#pragma unroll
    for (int ii = 0; ii < 16; ii++) { v[ii] = __shfl(alpha, i0 + ii) + tr[ii]; m1 = fmaxf(m1, v[ii]); }
    float m2 = fmaxf(m1, __shfl_xor(m1, 32));
    float sum = 0.f;
#pragma unroll
    for (int ii = 0; ii < 16; ii++) sum += __builtin_amdgcn_exp2f((v[ii] - m2) * LOG2E);
    sum += __shfl_xor(sum, 32);
    alpha = m2 + LN2 * __builtin_amdgcn_logf(sum) + e;
  }
  float mz = alpha;
#pragma unroll
  for (int m = 16; m; m >>= 1) mz = fmaxf(mz, __shfl_xor(mz, m));
  float sz = __builtin_amdgcn_exp2f((alpha - mz) * LOG2E);
#pragma unroll
  for (int m = 16; m; m >>= 1) sz += __shfl_xor(sz, m);
  float logz = mz + LN2 * __builtin_amdgcn_logf(sz);
  if (lane == 0) out[b] = logz - rs;
}

// ---------------- launch ----------------
extern "C" void kernel_launch(void* const* d_in, const int* in_sizes, int n_in,
                              void* d_out, int out_size, void* d_ws, size_t ws_size,
                              hipStream_t stream) {
  const float* emb   = (const float*)d_in[0];
  const float* Wih_f = (const float*)d_in[1];
  const float* Whh_f = (const float*)d_in[2];
  const float* bih_f = (const float*)d_in[3];
  const float* bhh_f = (const float*)d_in[4];
  const float* Wih_b = (const float*)d_in[5];
  const float* Whh_b = (const float*)d_in[6];
  const float* bih_b = (const float*)d_in[7];
  const float* bhh_b = (const float*)d_in[8];
  const float* Wout  = (const float*)d_in[9];
  const float* bout  = (const float*)d_in[10];
  const float* trans = (const float*)d_in[11];
  const int* sent = (const int*)d_in[12];
  const int* tags = (const int*)d_in[13];
  const int* lens = (const int*)d_in[14];
  float* out = (float*)d_out;

  // workspace layout (bytes), total 87,048,192
  char* ws = (char*)d_ws;
  if (ws_size < 87048192ull) return;
  unsigned short* gx      = (unsigned short*)(ws);                // 67,108,864
  unsigned short* emit_f  = (unsigned short*)(ws + 67108864);     //  8,388,608
  unsigned short* emit_b  = (unsigned short*)(ws + 75497472);     //  8,388,608
  unsigned short* wih_bf  = (unsigned short*)(ws + 83886080);     //  1,048,576
  unsigned char*  whh8    = (unsigned char*)(ws + 84934656);      //    524,288
  unsigned char*  wout8   = (unsigned char*)(ws + 85458944);      //     16,384
  unsigned short* h_state = (unsigned short*)(ws + 85475328);     //    524,288
  float*          c_state = (float*)(ws + 85999616);              //  1,048,576

  cvt_weights<<<1040, 256, 0, stream>>>(Wih_f, Wih_b, Whh_f, Whh_b, Wout,
                                        wih_bf, whh8, wout8);
  for (int c = 0; c < 8; c++) {
    gx_gemm<<<dim3(256, 2), 512, 0, stream>>>(
        emb, sent, lens, wih_bf, bih_f, bhh_f, bih_b, bhh_b, gx, c * 64);
    lstm_rec<<<64, 512, 0, stream>>>(
        gx, whh8, wout8, bout, lens, emit_f, emit_b, h_state, c_state,
        c * 64, c == 0 ? 1 : 0);
  }
  crf_kernel<<<256, 64, 0, stream>>>(emit_f, emit_b, trans, tags, lens, out);
}